// Round 5
// baseline (647.251 us; speedup 1.0000x reference)
//
#include <hip/hip_runtime.h>

#define S_LEN   2048
#define HID     4096
#define NHEADS  32
#define NKVH    8
#define HDIM    128
#define NQKV    6144          // NKV*(QPK+2)*HD = 8*6*128
#define ATT_SCALE (1.0f/128.0f)

typedef unsigned short u16;
typedef __attribute__((ext_vector_type(8))) __bf16 bf16x8;
typedef __attribute__((ext_vector_type(4))) float  f32x4;

__device__ __forceinline__ u16 f2bf(float f) {
    union { float f; unsigned u; } x; x.f = f;
    unsigned u = x.u;
    u += 0x7fffu + ((u >> 16) & 1u);   // round-to-nearest-even
    return (u16)(u >> 16);
}
__device__ __forceinline__ float bf2f(u16 v) {
    union { unsigned u; float f; } x; x.u = ((unsigned)v) << 16; return x.f;
}

// ---------------- fp32 -> bf16 conversion ----------------
__global__ __launch_bounds__(256) void cvt_bf16_kernel(const float* __restrict__ in,
                                                       u16* __restrict__ out, int n4) {
    int stride = gridDim.x * blockDim.x;
    for (int i = blockIdx.x * blockDim.x + threadIdx.x; i < n4; i += stride) {
        float4 v = *(const float4*)(in + (size_t)i * 4);
        ushort4 o = make_ushort4(f2bf(v.x), f2bf(v.y), f2bf(v.z), f2bf(v.w));
        *(ushort4*)(out + (size_t)i * 4) = o;
    }
}

// ---------------- bf16 GEMM (round-4 pipelined version, unchanged) ----------------
#define BM 128
#define BN 128
#define BK 32

template <bool OUT_BF16>
__global__ __launch_bounds__(256) void gemm_bt_kernel(
    const u16* __restrict__ A,   // M x K  bf16
    const u16* __restrict__ B,   // N x K  bf16
    const float* __restrict__ bias, // N
    void* __restrict__ Cout,     // M x N  (fp32 or bf16)
    int M, int N, int K)
{
    __shared__ u16 Alds[2][BM][BK];
    __shared__ u16 Blds[2][BN][BK];

    const int tid  = threadIdx.x;
    const int wid  = tid >> 6;
    const int lane = tid & 63;
    const int ln   = lane & 15;
    const int quad = lane >> 4;
    const int wm   = (wid >> 1) * 64;
    const int wn   = (wid & 1) * 64;
    const int tileM = blockIdx.y * BM;
    const int tileN = blockIdx.x * BN;

    const int srow = lane >> 2;                            // 0..15
    const int scol = ((lane & 3) ^ ((srow >> 1) & 3)) * 8; // swizzled source column

    f32x4 acc[4][4];
    #pragma unroll
    for (int i = 0; i < 4; i++)
        #pragma unroll
        for (int j = 0; j < 4; j++) {
            f32x4 z = {0.f, 0.f, 0.f, 0.f};
            acc[i][j] = z;
        }

    auto stage = [&](int k, int buf) {
        const int k0 = k * BK;
        #pragma unroll
        for (int p = 0; p < 2; p++) {
            int r = p * 64 + wid * 16;
            const u16* ga = A + (size_t)(tileM + r + srow) * K + k0 + scol;
            const u16* gb = B + (size_t)(tileN + r + srow) * K + k0 + scol;
            __builtin_amdgcn_global_load_lds(
                (const __attribute__((address_space(1))) void*)ga,
                (__attribute__((address_space(3))) void*)&Alds[buf][r][0], 16, 0, 0);
            __builtin_amdgcn_global_load_lds(
                (const __attribute__((address_space(1))) void*)gb,
                (__attribute__((address_space(3))) void*)&Blds[buf][r][0], 16, 0, 0);
        }
    };

    const int nIter = K / BK;
    stage(0, 0);

    const int pc = (quad ^ ((ln >> 1) & 3)) * 8;

    for (int k = 0; k < nIter; k++) {
        const int buf = k & 1;
        __syncthreads();
        if (k + 1 < nIter) stage(k + 1, buf ^ 1);

        bf16x8 af[4], bfr[4];
        #pragma unroll
        for (int i = 0; i < 4; i++)
            af[i] = *(const bf16x8*)(&Alds[buf][wm + i * 16 + ln][pc]);
        #pragma unroll
        for (int j = 0; j < 4; j++)
            bfr[j] = *(const bf16x8*)(&Blds[buf][wn + j * 16 + ln][pc]);
        #pragma unroll
        for (int i = 0; i < 4; i++)
            #pragma unroll
            for (int j = 0; j < 4; j++)
                acc[i][j] = __builtin_amdgcn_mfma_f32_16x16x32_bf16(af[i], bfr[j], acc[i][j], 0, 0, 0);
    }

    #pragma unroll
    for (int i = 0; i < 4; i++) {
        #pragma unroll
        for (int j = 0; j < 4; j++) {
            int n = tileN + wn + j * 16 + ln;
            float bv = bias[n];
            #pragma unroll
            for (int r = 0; r < 4; r++) {
                int m = tileM + wm + i * 16 + quad * 4 + r;
                float v = acc[i][j][r] + bv;
                if (OUT_BF16)
                    ((u16*)Cout)[(size_t)m * N + n] = f2bf(v);
                else
                    ((float*)Cout)[(size_t)m * N + n] = v;
            }
        }
    }
}

// ---------------- RoPE + split qkv (q and k only; v handled by transpose) ----------
__global__ __launch_bounds__(128) void rope_split_kernel(
    const u16* __restrict__ qkv, const int* __restrict__ positions,
    u16* __restrict__ qb_o, u16* __restrict__ kb_o)
{
    const int d   = threadIdx.x;     // 0..127
    const int pos = blockIdx.x;      // 0..S-1
    const int hy  = blockIdx.y;      // 0..39
    const float p = (float)positions[pos];

    const u16* src;
    u16* dst;
    if (hy < NHEADS) {                        // q head
        int kv = hy >> 2, qi = hy & 3;
        src = qkv + (size_t)pos * NQKV + (kv * 6 + qi) * HDIM;
        dst = qb_o + ((size_t)hy * S_LEN + pos) * HDIM;
    } else {                                  // k head
        int kv = hy - NHEADS;
        src = qkv + (size_t)pos * NQKV + (kv * 6 + 4) * HDIM;
        dst = kb_o + ((size_t)kv * S_LEN + pos) * HDIM;
    }
    int d2 = d & 63;
    float inv = expf(-(float)d2 * (13.815510557964274f / 64.0f)); // 1e6^(-d2/64)
    float fr = p * inv;
    float s, c;
    sincosf(fr, &s, &c);
    float x1 = bf2f(src[d2]);
    float x2 = bf2f(src[d2 + 64]);
    float o = (d < 64) ? (x1 * c - x2 * s) : (x2 * c + x1 * s);
    dst[d] = f2bf(o);
}

// ---------------- V transpose: qkv(S,NQKV) v-slice -> VT (NKV, HD, S) --------------
__global__ __launch_bounds__(256) void v_transpose_kernel(
    const u16* __restrict__ qkv, u16* __restrict__ vT)
{
    __shared__ u16 Ls[64][136];
    const int tile = blockIdx.x;     // pos tile (64 wide)
    const int kvh  = blockIdx.y;     // 0..7
    const int tid  = threadIdx.x;

    {   // load 64 pos x 128 d, coalesced
        int r = tid >> 4;                 // 0..15
        int c = (tid & 15) * 8;
        #pragma unroll
        for (int p = 0; p < 4; p++) {
            int row = p * 16 + r;
            *(uint4*)(&Ls[row][c]) =
                *(const uint4*)(qkv + (size_t)(tile * 64 + row) * NQKV + (kvh * 6 + 5) * HDIM + c);
        }
    }
    __syncthreads();
    {   // store d-major; rotated scalar LDS reads (conflict-free)
        int l = tid & 7;
        int pos0 = l * 8;
        #pragma unroll
        for (int p = 0; p < 4; p++) {
            int d = p * 32 + (tid >> 3);
            u16 tmp[8];
            #pragma unroll
            for (int j = 0; j < 8; j++) {
                int jj = (j + l) & 7;
                tmp[jj] = Ls[pos0 + jj][d];
            }
            *(uint4*)(vT + ((size_t)kvh * HDIM + d) * S_LEN + tile * 64 + pos0) = *(uint4*)tmp;
        }
    }
}

// ---------------- blocksparse flash attention ----------------
// grid (S/64, NH); block 256 (4 waves). Wave w owns query rows w*16..w*16+15.
// Q fragments in registers; K/V^T register-prefetched (next selected block) then
// committed to LDS; 2 barriers per k-block.
#define LDK 136   // 128+8
#define LDV 72    // 64+8
__global__ __launch_bounds__(256) void attn_bs_kernel(
    const u16* __restrict__ Q,   // (NH, S, HD) bf16
    const u16* __restrict__ K,   // (NKV, S, HD)
    const u16* __restrict__ VT,  // (NKV, HD, S)  pre-transposed
    u16* __restrict__ O)         // (S, NH*HD) bf16
{
    __shared__ u16 Ks[64][LDK];
    __shared__ u16 Vt[128][LDV];
    __shared__ u16 Ps[4][16][LDV];

    const int qb = blockIdx.x;
    const int h  = blockIdx.y;
    const int kv = h >> 2;
    const int tid  = threadIdx.x;
    const int w    = tid >> 6;
    const int lane = tid & 63;
    const int ln   = lane & 15;
    const int quad = lane >> 4;

    // Q fragments in registers (wave's 16 rows)
    bf16x8 qf[4];
    {
        const u16* Qg = Q + ((size_t)h * S_LEN + qb * 64 + w * 16 + ln) * HDIM;
        #pragma unroll
        for (int ks = 0; ks < 4; ks++)
            qf[ks] = *(const bf16x8*)(Qg + ks * 32 + quad * 8);
    }

    // staging coords
    const int krow = tid >> 4;          // 0..15
    const int kcol = (tid & 15) * 8;
    const int vrow = tid >> 3;          // 0..31
    const int vcol = (tid & 7) * 8;
    const u16* Kbase = K  + (size_t)kv * S_LEN * HDIM;
    const u16* Vbase = VT + (size_t)kv * HDIM * S_LEN;

    uint4 kreg[4], vreg[4];
    auto prefetch = [&](int kb) {
        const u16* Kg = Kbase + (size_t)kb * 64 * HDIM;
        #pragma unroll
        for (int p = 0; p < 4; p++)
            kreg[p] = *(const uint4*)(Kg + (size_t)(p * 16 + krow) * HDIM + kcol);
        #pragma unroll
        for (int p = 0; p < 4; p++)
            vreg[p] = *(const uint4*)(Vbase + (size_t)(p * 32 + vrow) * S_LEN + kb * 64 + vcol);
    };
    auto commit = [&]() {
        #pragma unroll
        for (int p = 0; p < 4; p++)
            *(uint4*)(&Ks[p * 16 + krow][kcol]) = kreg[p];
        #pragma unroll
        for (int p = 0; p < 4; p++)
            *(uint4*)(&Vt[p * 32 + vrow][vcol]) = vreg[p];
    };

    f32x4 oacc[8];
    #pragma unroll
    for (int n = 0; n < 8; n++) { f32x4 z = {0.f,0.f,0.f,0.f}; oacc[n] = z; }
    float mrow[4] = {-1e30f, -1e30f, -1e30f, -1e30f};
    float lrow[4] = {0.f, 0.f, 0.f, 0.f};

    auto sel = [&](int b) { return (qb - b < 16) || (((b + h + 1) & 7) == 0); };

    int kb = 0;
    while (!sel(kb)) kb++;              // qb itself is always selected
    prefetch(kb);

    while (kb >= 0) {
        int nkb = -1;
        for (int b = kb + 1; b <= qb; b++) if (sel(b)) { nkb = b; break; }

        __syncthreads();                // prior iteration's LDS reads done
        commit();
        if (nkb >= 0) prefetch(nkb);    // latency hidden behind compute
        __syncthreads();                // K/Vt resident

        // S = Q K^T  (wave's 16 rows x 64 keys)
        f32x4 sacc[4];
        #pragma unroll
        for (int jj = 0; jj < 4; jj++) { f32x4 z = {0.f,0.f,0.f,0.f}; sacc[jj] = z; }
        #pragma unroll
        for (int ks = 0; ks < 4; ks++) {
            #pragma unroll
            for (int jj = 0; jj < 4; jj++) {
                bf16x8 bk = *(const bf16x8*)(&Ks[jj * 16 + ln][ks * 32 + quad * 8]);
                sacc[jj] = __builtin_amdgcn_mfma_f32_16x16x32_bf16(qf[ks], bk, sacc[jj], 0, 0, 0);
            }
        }

        // scale + diagonal causal mask + online softmax; write P to LDS (wave-private)
        #pragma unroll
        for (int r = 0; r < 4; r++) {
            float pv[4];
            float mx = -1e30f;
            const int qrow = w * 16 + quad * 4 + r;
            #pragma unroll
            for (int jj = 0; jj < 4; jj++) {
                float s = sacc[jj][r] * ATT_SCALE;
                if (kb == qb && (jj * 16 + ln) > qrow) s = -1e30f;
                pv[jj] = s;
                mx = fmaxf(mx, s);
            }
            #pragma unroll
            for (int off = 1; off < 16; off <<= 1)
                mx = fmaxf(mx, __shfl_xor(mx, off, 64));
            float mnew  = fmaxf(mrow[r], mx);
            float alpha = __expf(mrow[r] - mnew);
            float sum = 0.f;
            #pragma unroll
            for (int jj = 0; jj < 4; jj++) {
                float pe = __expf(pv[jj] - mnew);
                pv[jj] = pe;
                sum += pe;
            }
            #pragma unroll
            for (int off = 1; off < 16; off <<= 1)
                sum += __shfl_xor(sum, off, 64);
            lrow[r] = lrow[r] * alpha + sum;
            mrow[r] = mnew;
            #pragma unroll
            for (int n = 0; n < 8; n++) oacc[n][r] *= alpha;
            #pragma unroll
            for (int jj = 0; jj < 4; jj++)
                Ps[w][quad * 4 + r][jj * 16 + ln] = f2bf(pv[jj]);
        }
        // no barrier: Ps[w] is wave-private, compiler inserts lgkmcnt wait

        // O += P V   (P: 16x64 A-layout; V via Vt: B[n=dim][k=key])
        #pragma unroll
        for (int kk = 0; kk < 2; kk++) {
            bf16x8 ap = *(const bf16x8*)(&Ps[w][ln][kk * 32 + quad * 8]);
            #pragma unroll
            for (int n = 0; n < 8; n++) {
                bf16x8 bv = *(const bf16x8*)(&Vt[n * 16 + ln][kk * 32 + quad * 8]);
                oacc[n] = __builtin_amdgcn_mfma_f32_16x16x32_bf16(ap, bv, oacc[n], 0, 0, 0);
            }
        }

        kb = nkb;
    }

    // epilogue: O /= l, store bf16 (S, NH*HD)
    #pragma unroll
    for (int n = 0; n < 8; n++) {
        #pragma unroll
        for (int r = 0; r < 4; r++) {
            int row = w * 16 + quad * 4 + r;
            int pos = qb * 64 + row;
            float o = oacc[n][r] / lrow[r];
            O[(size_t)pos * (NHEADS * HDIM) + h * HDIM + n * 16 + ln] = f2bf(o);
        }
    }
}

// ---------------- launch ----------------
extern "C" void kernel_launch(void* const* d_in, const int* in_sizes, int n_in,
                              void* d_out, int out_size, void* d_ws, size_t ws_size,
                              hipStream_t stream) {
    const int*   positions = (const int*)d_in[0];
    const float* hidden    = (const float*)d_in[1];
    const float* w_qkv     = (const float*)d_in[2];
    const float* b_qkv     = (const float*)d_in[3];
    const float* w_dense   = (const float*)d_in[4];
    const float* b_dense   = (const float*)d_in[5];
    float* out = (float*)d_out;

    char* ws = (char*)d_ws;
    u16* ws_h    = (u16*)(ws);                    // 2048*4096*2   = 16,777,216
    u16* ws_wqkv = (u16*)(ws + 16777216);         // 6144*4096*2  = 50,331,648
    u16* ws_wd   = (u16*)(ws + 67108864);         // 4096*4096*2  = 33,554,432
    u16* ws_qkv  = (u16*)(ws + 100663296);        // 2048*6144*2  = 25,165,824 (bf16)
    u16* ws_q    = (u16*)(ws + 125829120);        // 32*2048*128*2= 16,777,216
    u16* ws_k    = (u16*)(ws + 142606336);        // 8*2048*128*2 =  4,194,304
    u16* ws_vT   = (u16*)(ws + 146800640);        // 8*128*2048*2 =  4,194,304
    u16* ws_attn = (u16*)(ws + 150994944);        // 2048*4096*2  = 16,777,216

    cvt_bf16_kernel<<<1024, 256, 0, stream>>>(hidden,  ws_h,    (S_LEN * HID) / 4);
    cvt_bf16_kernel<<<2048, 256, 0, stream>>>(w_qkv,   ws_wqkv, (NQKV * HID) / 4);
    cvt_bf16_kernel<<<2048, 256, 0, stream>>>(w_dense, ws_wd,   (HID * HID) / 4);

    gemm_bt_kernel<true><<<dim3(NQKV / BN, S_LEN / BM), 256, 0, stream>>>(
        ws_h, ws_wqkv, b_qkv, ws_qkv, S_LEN, NQKV, HID);

    rope_split_kernel<<<dim3(S_LEN, NHEADS + NKVH), 128, 0, stream>>>(
        ws_qkv, positions, ws_q, ws_k);

    v_transpose_kernel<<<dim3(S_LEN / 64, NKVH), 256, 0, stream>>>(ws_qkv, ws_vT);

    attn_bs_kernel<<<dim3(S_LEN / 64, NHEADS), 256, 0, stream>>>(ws_q, ws_k, ws_vT, ws_attn);

    gemm_bt_kernel<false><<<dim3(HID / BN, S_LEN / BM), 256, 0, stream>>>(
        ws_attn, ws_wd, b_dense, out, S_LEN, HID, HID);
}